// Round 5
// baseline (188.445 us; speedup 1.0000x reference)
//
#include <hip/hip_runtime.h>
#include <hip/hip_bf16.h>

// out[bn,e] = relu(relu(hp[bn]+ep[e]+b1) @ W2 + b2) @ W3 + b3
// R5: B-in-registers GEMM. Wave = 64 rows x 32 cols, full K=512 of W2 held in
// 128 VGPRs -> K-loop has zero global loads and zero addressing VALU (ds_read
// with immediate offsets). x1 double-buffered in LDS, staging pipelined into
// the MFMA loop, 1 barrier per tile. Col-halves combine via f32 partials.

typedef __attribute__((ext_vector_type(8))) short bf16x8;   // 8 bf16
typedef __attribute__((ext_vector_type(4))) float f32x4;    // MFMA acc

static __device__ __forceinline__ ushort2 pk_bf16(float a, float b) {
  union { __hip_bfloat162 h; ushort2 u; } c;
  c.h = __float22bfloat162_rn(make_float2(a, b));
  return c.u;
}
static __device__ __forceinline__ float bf2f(unsigned short u) {
  union { unsigned int i; float f; } c;
  c.i = ((unsigned int)u) << 16;
  return c.f;
}

// ---------------- fused prep (352 blocks x 256 thr) ----------------
// blocks 0..255  : hpb rows (2/blk)  hpb[r][k] = bf16(sum_h h[r][h]*W1[h][k] + b1[k])
// blocks 256..287: epb rows (8/blk)  epb[e][k] = bf16(sum_d e[e][d]*W1[256+d][k])
// blocks 288..351: w2f pack (64x64 W2 tile -> bf16 B-frag records)
//   record(jg,ks): lane l holds W2[k = ks*32+(l>>4)*8 + u][col = jg*16+(l&15)], u=0..7
__global__ __launch_bounds__(256) void k_prep(
    const float* __restrict__ h_all, const float* __restrict__ e_feat,
    const float* __restrict__ W1, const float* __restrict__ b1,
    const float* __restrict__ W2,
    unsigned short* __restrict__ hpb, unsigned short* __restrict__ epb,
    unsigned short* __restrict__ w2f) {
  __shared__ float sm[64 * 68];   // 17408 B, reused per role
  const int t = threadIdx.x;
  const int b = blockIdx.x;

  if (b < 256) {                      // ---- hp part: 2 rows, bf16 out
    const int r0 = b * 2;
    float (*hs)[256] = (float(*)[256])sm;
    hs[0][t] = h_all[(size_t)r0 * 256 + t];
    hs[1][t] = h_all[(size_t)(r0 + 1) * 256 + t];
    __syncthreads();
    float2 a0 = make_float2(0.f, 0.f), a1 = make_float2(0.f, 0.f);
    #pragma unroll 2
    for (int k = 0; k < 256; k += 4) {
      float2 w0 = *(const float2*)(W1 + (size_t)k * 512 + 2 * t);
      float2 w1 = *(const float2*)(W1 + (size_t)(k + 1) * 512 + 2 * t);
      float2 w2v = *(const float2*)(W1 + (size_t)(k + 2) * 512 + 2 * t);
      float2 w3v = *(const float2*)(W1 + (size_t)(k + 3) * 512 + 2 * t);
      float h00 = hs[0][k], h01 = hs[0][k + 1], h02 = hs[0][k + 2], h03 = hs[0][k + 3];
      float h10 = hs[1][k], h11 = hs[1][k + 1], h12 = hs[1][k + 2], h13 = hs[1][k + 3];
      a0.x = fmaf(h00, w0.x, a0.x); a0.y = fmaf(h00, w0.y, a0.y);
      a1.x = fmaf(h10, w0.x, a1.x); a1.y = fmaf(h10, w0.y, a1.y);
      a0.x = fmaf(h01, w1.x, a0.x); a0.y = fmaf(h01, w1.y, a0.y);
      a1.x = fmaf(h11, w1.x, a1.x); a1.y = fmaf(h11, w1.y, a1.y);
      a0.x = fmaf(h02, w2v.x, a0.x); a0.y = fmaf(h02, w2v.y, a0.y);
      a1.x = fmaf(h12, w2v.x, a1.x); a1.y = fmaf(h12, w2v.y, a1.y);
      a0.x = fmaf(h03, w3v.x, a0.x); a0.y = fmaf(h03, w3v.y, a0.y);
      a1.x = fmaf(h13, w3v.x, a1.x); a1.y = fmaf(h13, w3v.y, a1.y);
    }
    float2 bv = *(const float2*)(b1 + 2 * t);
    *(ushort2*)(hpb + (size_t)r0 * 512 + 2 * t) = pk_bf16(a0.x + bv.x, a0.y + bv.y);
    *(ushort2*)(hpb + (size_t)(r0 + 1) * 512 + 2 * t) = pk_bf16(a1.x + bv.x, a1.y + bv.y);
  } else if (b < 288) {               // ---- ep part: 8 rows, bf16 out
    const int r0 = (b - 256) * 8;
    sm[t] = e_feat[(size_t)r0 * 64 + t];
    sm[256 + t] = e_feat[(size_t)r0 * 64 + 256 + t];
    __syncthreads();
    float2 acc[8];
    #pragma unroll
    for (int i = 0; i < 8; ++i) acc[i] = make_float2(0.f, 0.f);
    for (int k = 0; k < 64; ++k) {
      float2 wv = *(const float2*)(W1 + (size_t)(256 + k) * 512 + 2 * t);
      #pragma unroll
      for (int i = 0; i < 8; ++i) {
        acc[i].x = fmaf(sm[i * 64 + k], wv.x, acc[i].x);
        acc[i].y = fmaf(sm[i * 64 + k], wv.y, acc[i].y);
      }
    }
    #pragma unroll
    for (int i = 0; i < 8; ++i)
      *(ushort2*)(epb + (size_t)(r0 + i) * 512 + 2 * t) = pk_bf16(acc[i].x, acc[i].y);
  } else {                            // ---- w2f pack
    const int bb = b - 288;           // 0..63
    const int k0 = (bb >> 3) * 64;
    const int c0 = (bb & 7) * 64;
    #pragma unroll
    for (int rr = 0; rr < 4; ++rr) {
      const int row = rr * 16 + (t >> 4);
      float4 v = *(const float4*)(W2 + (size_t)(k0 + row) * 512 + c0 + (t & 15) * 4);
      *(float4*)(&sm[row * 68 + (t & 15) * 4]) = v;
    }
    __syncthreads();
    #pragma unroll
    for (int s2 = 0; s2 < 2; ++s2) {
      const int s = t * 2 + s2;       // 0..511 (8 records x 64 lanes)
      const int rec = s >> 6, l = s & 63;
      const int jg = (c0 >> 4) + (rec & 3);
      const int ksg = (k0 >> 5) + (rec >> 2);
      const int cl = (rec & 3) * 16 + (l & 15);
      const int kl = (rec >> 2) * 32 + (l >> 4) * 8;
      union { ushort2 o[4]; uint4 v; } u;
      #pragma unroll
      for (int uu = 0; uu < 4; ++uu)
        u.o[uu] = pk_bf16(sm[(kl + 2 * uu) * 68 + cl], sm[(kl + 2 * uu + 1) * 68 + cl]);
      *(uint4*)(w2f + ((size_t)(jg * 16 + ksg) * 64 + l) * 8) = u.v;
    }
  }
}

// ---------------- main fused kernel ----------------
// 512 blocks x 512 thr (8 waves). Block: cg = col-half (256 cols), stream of 8
// row-bands (64 rows each). Wave w: cols cg*256 + w*32. Full-K W2 slice in regs.
__global__ __launch_bounds__(512, 2) void k_main(
    const unsigned short* __restrict__ hpb, const unsigned short* __restrict__ epb,
    const unsigned short* __restrict__ w2f, const float* __restrict__ b2,
    const float* __restrict__ W3, float* __restrict__ pws) {
  __shared__ unsigned short x1s[2][64 * 512];   // 2 x 64 KiB, XOR-swizzled
  __shared__ float osum[2][8][64];              // 4 KiB, dbuf per tile parity

  const int t = threadIdx.x;
  const int lane = t & 63;
  const int w = t >> 6;              // 0..7
  const int l15 = lane & 15, l4 = lane >> 4;
  const int p = lane & 7;            // == l15 & 7
  const int cg = blockIdx.x & 1;
  const int stream = blockIdx.x >> 1;

  // ---- B preload: bfr[j][ks] covers cols cg*256 + w*32 + j*16, all K
  bf16x8 bfr[2][16];
  {
    const unsigned short* wb = w2f + ((size_t)(cg * 16 + w * 2) * 16 * 64 + lane) * 8;
    #pragma unroll
    for (int j = 0; j < 2; ++j)
      #pragma unroll
      for (int ks = 0; ks < 16; ++ks)
        bfr[j][ks] = *(const bf16x8*)(wb + (size_t)(j * 16 + ks) * 512);
  }
  float b2v[2], w3v[2];
  #pragma unroll
  for (int j = 0; j < 2; ++j) {
    const int n = cg * 256 + w * 32 + j * 16 + l15;
    b2v[j] = b2[n];
    w3v[j] = W3[n];
  }

  // staging mapping: thread t -> chunk kk, row-base rb; swizzle (kk^rb) const/thread
  const int kk = t & 63;
  const int rb = t >> 6;
  unsigned short* sb[2];
  sb[0] = &x1s[0][rb * 512 + ((kk ^ rb) * 8)];
  sb[1] = &x1s[1][rb * 512 + ((kk ^ rb) * 8)];
  // a-frag read bases (even/odd ks), per buffer; all (i,ks) via imm offsets
  const int c0 = l4 ^ p;
  const unsigned short* ab[2][2];
  ab[0][0] = &x1s[0][l15 * 512 + c0 * 8];
  ab[0][1] = &x1s[0][l15 * 512 + (c0 ^ 4) * 8];
  ab[1][0] = &x1s[1][l15 * 512 + c0 * 8];
  ab[1][1] = &x1s[1][l15 * 512 + (c0 ^ 4) * 8];

  // ---- initial stage: tile 0 into buf 0
  {
    const int tt0 = stream * 8;
    const unsigned short* hpr = hpb + (size_t)(tt0 >> 2) * 512 + kk * 8;
    const unsigned short* epr = epb + ((size_t)(((tt0 & 3) << 6) + rb)) * 512 + kk * 8;
    union { uint4 v; unsigned short s[8]; } hv, ev, nx, ov;
    hv.v = *(const uint4*)hpr;
    ev.v = *(const uint4*)epr;
    float hf[8];
    #pragma unroll
    for (int u = 0; u < 8; ++u) hf[u] = bf2f(hv.s[u]);
    #pragma unroll
    for (int s = 0; s < 8; ++s) {
      if (s < 7) nx.v = *(const uint4*)(epr + (size_t)(s + 1) * 4096);
      #pragma unroll
      for (int u = 0; u < 4; ++u) {
        ushort2 pk = pk_bf16(fmaxf(bf2f(ev.s[2 * u]) + hf[2 * u], 0.f),
                             fmaxf(bf2f(ev.s[2 * u + 1]) + hf[2 * u + 1], 0.f));
        ov.s[2 * u] = pk.x;
        ov.s[2 * u + 1] = pk.y;
      }
      *(uint4*)(sb[0] + (size_t)s * 4096) = ov.v;
      ev = nx;
    }
  }
  __syncthreads();

  // ---- tile loop: 8 row-bands
  #pragma unroll 1
  for (int st = 0; st < 8; ++st) {
    const int q = st & 1, qn = q ^ 1;
    const int stn = (st < 7) ? st + 1 : st;    // last tile: redundant restage
    const int ttn = stream * 8 + stn;
    const unsigned short* hpr = hpb + (size_t)(ttn >> 2) * 512 + kk * 8;
    const unsigned short* epr = epb + ((size_t)(((ttn & 3) << 6) + rb)) * 512 + kk * 8;
    union { uint4 v; unsigned short s[8]; } hv, evc, evn, ov;
    hv.v = *(const uint4*)hpr;
    evc.v = *(const uint4*)epr;
    float hf[8];
    #pragma unroll
    for (int u = 0; u < 8; ++u) hf[u] = bf2f(hv.s[u]);

    f32x4 acc[4][2] = {};
    #pragma unroll
    for (int ks = 0; ks < 16; ++ks) {
      const int m = ks >> 1;
      bf16x8 a[4];
      #pragma unroll
      for (int i = 0; i < 4; ++i)
        a[i] = *(const bf16x8*)(ab[q][ks & 1] + i * 8192 + m * 64);
      #pragma unroll
      for (int i = 0; i < 4; ++i) {
        acc[i][0] = __builtin_amdgcn_mfma_f32_16x16x32_bf16(a[i], bfr[0][ks], acc[i][0], 0, 0, 0);
        acc[i][1] = __builtin_amdgcn_mfma_f32_16x16x32_bf16(a[i], bfr[1][ks], acc[i][1], 0, 0, 0);
      }
      // pipelined staging of next tile into buf qn
      if ((ks & 1) == 0) {
        const int s1 = (ks >> 1) + 1;
        if (s1 < 8) evn.v = *(const uint4*)(epr + (size_t)s1 * 4096);
      } else {
        const int s = ks >> 1;
        #pragma unroll
        for (int u = 0; u < 4; ++u) {
          ushort2 pk = pk_bf16(fmaxf(bf2f(evc.s[2 * u]) + hf[2 * u], 0.f),
                               fmaxf(bf2f(evc.s[2 * u + 1]) + hf[2 * u + 1], 0.f));
          ov.s[2 * u] = pk.x;
          ov.s[2 * u + 1] = pk.y;
        }
        *(uint4*)(sb[qn] + (size_t)s * 4096) = ov.v;
        evc = evn;
      }
    }

    // ---- epilogue: per-row partial of relu(acc+b2)*W3, reduce over col-lanes
    float part[16];
    #pragma unroll
    for (int u = 0; u < 16; ++u) part[u] = 0.f;
    #pragma unroll
    for (int j = 0; j < 2; ++j)
      #pragma unroll
      for (int i = 0; i < 4; ++i)
        #pragma unroll
        for (int r = 0; r < 4; ++r)
          part[i * 4 + r] = fmaf(fmaxf(acc[i][j][r] + b2v[j], 0.f), w3v[j], part[i * 4 + r]);
    #pragma unroll
    for (int u = 0; u < 16; ++u) {
      float v = part[u];
      v += __shfl_xor(v, 1);
      v += __shfl_xor(v, 2);
      v += __shfl_xor(v, 4);
      v += __shfl_xor(v, 8);
      part[u] = v;
    }
    if (l15 == 0) {
      #pragma unroll
      for (int i = 0; i < 4; ++i)
        #pragma unroll
        for (int r = 0; r < 4; ++r)
          osum[q][w][i * 16 + l4 * 4 + r] = part[i * 4 + r];
    }
    __syncthreads();   // staging into qn done; osum[q] visible
    if (t < 64) {
      float s = 0.f;
      #pragma unroll
      for (int ww = 0; ww < 8; ++ww) s += osum[q][ww][t];
      pws[(size_t)cg * 131072 + (size_t)(stream * 8 + st) * 64 + t] = s;
    }
  }
}

// ---------------- combine: out = pws(cg0) + pws(cg1) + b3 ----------------
__global__ __launch_bounds__(256) void k_comb(const float* __restrict__ pws,
                                              const float* __restrict__ b3,
                                              float* __restrict__ out) {
  const int i = blockIdx.x * 256 + threadIdx.x;
  out[i] = pws[i] + pws[131072 + i] + b3[0];
}

extern "C" void kernel_launch(void* const* d_in, const int* in_sizes, int n_in,
                              void* d_out, int out_size, void* d_ws, size_t ws_size,
                              hipStream_t stream) {
  const float* h_all  = (const float*)d_in[0];   // (8,64,256)
  const float* e_feat = (const float*)d_in[1];   // (256,64)
  const float* W1     = (const float*)d_in[2];   // (320,512)
  const float* b1     = (const float*)d_in[3];   // (512,)
  const float* W2     = (const float*)d_in[4];   // (512,512)
  const float* b2     = (const float*)d_in[5];   // (512,)
  const float* W3     = (const float*)d_in[6];   // (512,1)
  const float* b3     = (const float*)d_in[7];   // (1,)
  float* out = (float*)d_out;                    // 131072 f32

  // ws: hpb 512KB | epb 256KB | w2f 512KB | pws 1MB  (2.25 MB)
  unsigned short* hpb = (unsigned short*)d_ws;
  unsigned short* epb = hpb + 512 * 512;
  unsigned short* w2f = epb + 256 * 512;
  float* pws = (float*)(w2f + 512 * 512);

  hipLaunchKernelGGL(k_prep, dim3(352), dim3(256), 0, stream,
                     h_all, e_feat, W1, b1, W2, hpb, epb, w2f);
  hipLaunchKernelGGL(k_main, dim3(512), dim3(512), 0, stream,
                     hpb, epb, w2f, b2, W3, pws);
  hipLaunchKernelGGL(k_comb, dim3(512), dim3(256), 0, stream,
                     pws, b3, out);
}

// Round 6
// 159.704 us; speedup vs baseline: 1.1800x; 1.1800x over previous
//
#include <hip/hip_runtime.h>
#include <hip/hip_bf16.h>

// out[bn,e] = relu(relu(hp[bn]+ep[e]+b1) @ W2 + b2) @ W3 + b3
// R6: 128-row x 512-col blocks (512 thr, 8 waves, wave tile 64x128).
// K split into 16 chunks of 32; x1 AND B double-buffered in LDS, one barrier
// per chunk. Global loads for chunk k+1 issue before the MFMA block. B L2
// traffic halves vs R4 and is decoupled from the MFMA window.

typedef __attribute__((ext_vector_type(8))) short bf16x8;   // 8 bf16
typedef __attribute__((ext_vector_type(4))) float f32x4;    // MFMA acc

static __device__ __forceinline__ ushort2 pk_bf16(float a, float b) {
  union { __hip_bfloat162 h; ushort2 u; } c;
  c.h = __float22bfloat162_rn(make_float2(a, b));
  return c.u;
}
static __device__ __forceinline__ float bf2f(unsigned short u) {
  union { unsigned int i; float f; } c;
  c.i = ((unsigned int)u) << 16;
  return c.f;
}

// ---------------- fused prep (352 blocks x 256 thr) ----------------
// blocks 0..255  : hpb rows (2/blk)  hpb[r][k] = bf16(sum_h h[r][h]*W1[h][k] + b1[k])
// blocks 256..287: epb rows (8/blk)  epb[e][k] = bf16(sum_d e[e][d]*W1[256+d][k])
// blocks 288..351: w2f pack (64x64 W2 tile -> bf16 B-frag records)
//   record(jg,ks): lane l holds W2[k = ks*32+(l>>4)*8 + u][col = jg*16+(l&15)], u=0..7
__global__ __launch_bounds__(256) void k_prep(
    const float* __restrict__ h_all, const float* __restrict__ e_feat,
    const float* __restrict__ W1, const float* __restrict__ b1,
    const float* __restrict__ W2,
    unsigned short* __restrict__ hpb, unsigned short* __restrict__ epb,
    unsigned short* __restrict__ w2f) {
  __shared__ float sm[64 * 68];   // 17408 B, reused per role
  const int t = threadIdx.x;
  const int b = blockIdx.x;

  if (b < 256) {                      // ---- hp part: 2 rows, bf16 out
    const int r0 = b * 2;
    float (*hs)[256] = (float(*)[256])sm;
    hs[0][t] = h_all[(size_t)r0 * 256 + t];
    hs[1][t] = h_all[(size_t)(r0 + 1) * 256 + t];
    __syncthreads();
    float2 a0 = make_float2(0.f, 0.f), a1 = make_float2(0.f, 0.f);
    #pragma unroll 2
    for (int k = 0; k < 256; k += 4) {
      float2 w0 = *(const float2*)(W1 + (size_t)k * 512 + 2 * t);
      float2 w1 = *(const float2*)(W1 + (size_t)(k + 1) * 512 + 2 * t);
      float2 w2v = *(const float2*)(W1 + (size_t)(k + 2) * 512 + 2 * t);
      float2 w3v = *(const float2*)(W1 + (size_t)(k + 3) * 512 + 2 * t);
      float h00 = hs[0][k], h01 = hs[0][k + 1], h02 = hs[0][k + 2], h03 = hs[0][k + 3];
      float h10 = hs[1][k], h11 = hs[1][k + 1], h12 = hs[1][k + 2], h13 = hs[1][k + 3];
      a0.x = fmaf(h00, w0.x, a0.x); a0.y = fmaf(h00, w0.y, a0.y);
      a1.x = fmaf(h10, w0.x, a1.x); a1.y = fmaf(h10, w0.y, a1.y);
      a0.x = fmaf(h01, w1.x, a0.x); a0.y = fmaf(h01, w1.y, a0.y);
      a1.x = fmaf(h11, w1.x, a1.x); a1.y = fmaf(h11, w1.y, a1.y);
      a0.x = fmaf(h02, w2v.x, a0.x); a0.y = fmaf(h02, w2v.y, a0.y);
      a1.x = fmaf(h12, w2v.x, a1.x); a1.y = fmaf(h12, w2v.y, a1.y);
      a0.x = fmaf(h03, w3v.x, a0.x); a0.y = fmaf(h03, w3v.y, a0.y);
      a1.x = fmaf(h13, w3v.x, a1.x); a1.y = fmaf(h13, w3v.y, a1.y);
    }
    float2 bv = *(const float2*)(b1 + 2 * t);
    *(ushort2*)(hpb + (size_t)r0 * 512 + 2 * t) = pk_bf16(a0.x + bv.x, a0.y + bv.y);
    *(ushort2*)(hpb + (size_t)(r0 + 1) * 512 + 2 * t) = pk_bf16(a1.x + bv.x, a1.y + bv.y);
  } else if (b < 288) {               // ---- ep part: 8 rows, bf16 out
    const int r0 = (b - 256) * 8;
    sm[t] = e_feat[(size_t)r0 * 64 + t];
    sm[256 + t] = e_feat[(size_t)r0 * 64 + 256 + t];
    __syncthreads();
    float2 acc[8];
    #pragma unroll
    for (int i = 0; i < 8; ++i) acc[i] = make_float2(0.f, 0.f);
    for (int k = 0; k < 64; ++k) {
      float2 wv = *(const float2*)(W1 + (size_t)(256 + k) * 512 + 2 * t);
      #pragma unroll
      for (int i = 0; i < 8; ++i) {
        acc[i].x = fmaf(sm[i * 64 + k], wv.x, acc[i].x);
        acc[i].y = fmaf(sm[i * 64 + k], wv.y, acc[i].y);
      }
    }
    #pragma unroll
    for (int i = 0; i < 8; ++i)
      *(ushort2*)(epb + (size_t)(r0 + i) * 512 + 2 * t) = pk_bf16(acc[i].x, acc[i].y);
  } else {                            // ---- w2f pack
    const int bb = b - 288;           // 0..63
    const int k0 = (bb >> 3) * 64;
    const int c0 = (bb & 7) * 64;
    #pragma unroll
    for (int rr = 0; rr < 4; ++rr) {
      const int row = rr * 16 + (t >> 4);
      float4 v = *(const float4*)(W2 + (size_t)(k0 + row) * 512 + c0 + (t & 15) * 4);
      *(float4*)(&sm[row * 68 + (t & 15) * 4]) = v;
    }
    __syncthreads();
    #pragma unroll
    for (int s2 = 0; s2 < 2; ++s2) {
      const int s = t * 2 + s2;       // 0..511 (8 records x 64 lanes)
      const int rec = s >> 6, l = s & 63;
      const int jg = (c0 >> 4) + (rec & 3);
      const int ksg = (k0 >> 5) + (rec >> 2);
      const int cl = (rec & 3) * 16 + (l & 15);
      const int kl = (rec >> 2) * 32 + (l >> 4) * 8;
      union { ushort2 o[4]; uint4 v; } u;
      #pragma unroll
      for (int uu = 0; uu < 4; ++uu)
        u.o[uu] = pk_bf16(sm[(kl + 2 * uu) * 68 + cl], sm[(kl + 2 * uu + 1) * 68 + cl]);
      *(uint4*)(w2f + ((size_t)(jg * 16 + ksg) * 64 + l) * 8) = u.v;
    }
  }
}

// ---------------- main fused kernel ----------------
// 1024 blocks x 512 thr (8 waves). Block = 128 rows (one bn, e-half) x 512 cols.
// Wave w = rq*4+cq: rows rq*64..+64, cols cq*128..+128. BK=32, 16 chunks,
// x1 (8 KB) and B (32 KB) double-buffered, 1 barrier/chunk.
__global__ __launch_bounds__(512, 2) void k_main(
    const unsigned short* __restrict__ hpb, const unsigned short* __restrict__ epb,
    const unsigned short* __restrict__ w2f, const float* __restrict__ b2,
    const float* __restrict__ W3, const float* __restrict__ b3,
    float* __restrict__ out) {
  __shared__ unsigned short x1s[2][128 * 32];   // 2 x 8 KB  (row*32 + swz-chunk)
  __shared__ unsigned short bs[2][32 * 512];    // 2 x 32 KB (rec*64+lane)*8
  __shared__ float osum[2][4][64];              // 2 KB

  const int t = threadIdx.x;
  const int lane = t & 63;
  const int w = t >> 6;          // 0..7
  const int rq = w >> 2;         // row quarter-pair (64 rows)
  const int cq = w & 3;          // col group (128 cols)
  const int l15 = lane & 15, l4 = lane >> 4;
  const int bn = blockIdx.x >> 1;
  const int e0 = (blockIdx.x & 1) << 7;

  // staging indices
  const int sr = t >> 2;         // x1 row 0..127
  const int sc = t & 3;          // x1 16B-chunk in row (k = sc*8)
  const unsigned short* eprow = epb + (size_t)(e0 + sr) * 512 + sc * 8;
  const unsigned short* hprow = hpb + (size_t)bn * 512 + sc * 8;
  unsigned short* x1w[2];
  x1w[0] = &x1s[0][sr * 32 + ((sc ^ (sr & 3)) * 8)];
  x1w[1] = &x1s[1][sr * 32 + ((sc ^ (sr & 3)) * 8)];
  // B staging: 4 slots/thread: s = i*512+t -> rec = s>>6, ln = s&63
  // a-frag read base: row rq*64 + i*16 + l15, chunk l4 ^ (l15&3)
  const int arow = rq * 64 + l15;
  const int achk = (l4 ^ (l15 & 3)) * 8;

  // ---- prologue: stage chunk 0 into buf 0
  {
    uint4 hv4 = *(const uint4*)(hprow);
    uint4 ev4 = *(const uint4*)(eprow);
    union { uint4 v; unsigned short s[8]; } hv, ev, ov;
    hv.v = hv4; ev.v = ev4;
    #pragma unroll
    for (int u = 0; u < 4; ++u) {
      ushort2 p = pk_bf16(fmaxf(bf2f(ev.s[2 * u]) + bf2f(hv.s[2 * u]), 0.f),
                          fmaxf(bf2f(ev.s[2 * u + 1]) + bf2f(hv.s[2 * u + 1]), 0.f));
      ov.s[2 * u] = p.x;
      ov.s[2 * u + 1] = p.y;
    }
    *(uint4*)x1w[0] = ov.v;
    #pragma unroll
    for (int i = 0; i < 4; ++i) {
      const int s = i * 512 + t;
      const int rec = s >> 6, ln = s & 63;
      uint4 bv = *(const uint4*)(w2f + ((size_t)(rec * 16 + 0) * 64 + ln) * 8);
      *(uint4*)(&bs[0][(size_t)(rec * 64 + ln) * 8]) = bv;
    }
  }
  __syncthreads();

  f32x4 acc[4][8] = {};
  #pragma unroll 1
  for (int kc = 0; kc < 16; ++kc) {
    const int q = kc & 1, qn = q ^ 1;
    const int kn = (kc < 15) ? kc + 1 : kc;
    // issue next-chunk global loads first (in flight over the MFMA block)
    uint4 hv4 = *(const uint4*)(hprow + kn * 32);
    uint4 ev4 = *(const uint4*)(eprow + kn * 32);
    uint4 bv4[4];
    #pragma unroll
    for (int i = 0; i < 4; ++i) {
      const int s = i * 512 + t;
      const int rec = s >> 6, ln = s & 63;
      bv4[i] = *(const uint4*)(w2f + ((size_t)(rec * 16 + kn) * 64 + ln) * 8);
    }
    // MFMA on buf q
    {
      bf16x8 a[4], b[8];
      #pragma unroll
      for (int i = 0; i < 4; ++i)
        a[i] = *(const bf16x8*)(&x1s[q][(arow + i * 16) * 32 + achk]);
      #pragma unroll
      for (int j = 0; j < 8; ++j)
        b[j] = *(const bf16x8*)(&bs[q][(size_t)((cq * 8 + j) * 64 + lane) * 8]);
      #pragma unroll
      for (int i = 0; i < 4; ++i)
        #pragma unroll
        for (int j = 0; j < 8; ++j)
          acc[i][j] = __builtin_amdgcn_mfma_f32_16x16x32_bf16(a[i], b[j], acc[i][j], 0, 0, 0);
    }
    // convert & write next chunk into buf qn
    if (kc < 15) {
      union { uint4 v; unsigned short s[8]; } hv, ev, ov;
      hv.v = hv4; ev.v = ev4;
      #pragma unroll
      for (int u = 0; u < 4; ++u) {
        ushort2 p = pk_bf16(fmaxf(bf2f(ev.s[2 * u]) + bf2f(hv.s[2 * u]), 0.f),
                            fmaxf(bf2f(ev.s[2 * u + 1]) + bf2f(hv.s[2 * u + 1]), 0.f));
        ov.s[2 * u] = p.x;
        ov.s[2 * u + 1] = p.y;
      }
      *(uint4*)x1w[qn] = ov.v;
      #pragma unroll
      for (int i = 0; i < 4; ++i) {
        const int s = i * 512 + t;
        const int rec = s >> 6, ln = s & 63;
        *(uint4*)(&bs[qn][(size_t)(rec * 64 + ln) * 8]) = bv4[i];
      }
    }
    __syncthreads();
  }

  // ---- fused epilogue: osum[row] = sum_n relu(acc + b2[n]) * W3[n]
  float part[16];
  #pragma unroll
  for (int u = 0; u < 16; ++u) part[u] = 0.f;
  #pragma unroll
  for (int j = 0; j < 8; ++j) {
    const int n = cq * 128 + j * 16 + l15;
    const float b2v = b2[n], w3v = W3[n];
    #pragma unroll
    for (int i = 0; i < 4; ++i)
      #pragma unroll
      for (int r = 0; r < 4; ++r)
        part[i * 4 + r] = fmaf(fmaxf(acc[i][j][r] + b2v, 0.f), w3v, part[i * 4 + r]);
  }
  #pragma unroll
  for (int u = 0; u < 16; ++u) {     // reduce over the 16 col-lanes (l15)
    float v = part[u];
    v += __shfl_xor(v, 1);
    v += __shfl_xor(v, 2);
    v += __shfl_xor(v, 4);
    v += __shfl_xor(v, 8);
    part[u] = v;
  }
  if (l15 == 0) {
    #pragma unroll
    for (int i = 0; i < 4; ++i)
      #pragma unroll
      for (int r = 0; r < 4; ++r)
        osum[rq][cq][i * 16 + l4 * 4 + r] = part[i * 4 + r];
  }
  __syncthreads();
  if (t < 128) {
    const int r2 = t >> 6, ri = t & 63;
    float s = b3[0] + osum[r2][0][ri] + osum[r2][1][ri] + osum[r2][2][ri] + osum[r2][3][ri];
    out[(size_t)bn * 256 + e0 + t] = s;
  }
}

extern "C" void kernel_launch(void* const* d_in, const int* in_sizes, int n_in,
                              void* d_out, int out_size, void* d_ws, size_t ws_size,
                              hipStream_t stream) {
  const float* h_all  = (const float*)d_in[0];   // (8,64,256)
  const float* e_feat = (const float*)d_in[1];   // (256,64)
  const float* W1     = (const float*)d_in[2];   // (320,512)
  const float* b1     = (const float*)d_in[3];   // (512,)
  const float* W2     = (const float*)d_in[4];   // (512,512)
  const float* b2     = (const float*)d_in[5];   // (512,)
  const float* W3     = (const float*)d_in[6];   // (512,1)
  const float* b3     = (const float*)d_in[7];   // (1,)
  float* out = (float*)d_out;                    // 131072 f32

  // ws: hpb 512KB bf16 | epb 256KB bf16 | w2f 512KB bf16
  unsigned short* hpb = (unsigned short*)d_ws;
  unsigned short* epb = hpb + 512 * 512;
  unsigned short* w2f = epb + 256 * 512;

  hipLaunchKernelGGL(k_prep, dim3(352), dim3(256), 0, stream,
                     h_all, e_feat, W1, b1, W2, hpb, epb, w2f);
  hipLaunchKernelGGL(k_main, dim3(1024), dim3(512), 0, stream,
                     hpb, epb, w2f, b2, W3, b3, out);
}